// Round 10
// baseline (162.456 us; speedup 1.0000x reference)
//
#include <hip/hip_runtime.h>
#include <hip/hip_cooperative_groups.h>

namespace cg = cooperative_groups;

typedef __attribute__((ext_vector_type(8))) short short8;
typedef __attribute__((ext_vector_type(16))) float f32x16;

#define NROWS_IN 1600
#define NI 5000
#define BB 32
#define DDk 4
#define SS 50
#define NTILES 79
#define NBM 128            // mid blocks (b,d)
#define NBC 316            // cand blocks (tile,d)
#define NBLK (NBM + NBC)   // 444

__device__ __forceinline__ unsigned short f2bf(float f) {
    unsigned int u = __float_as_uint(f);
    u = (u + 0x7FFFu + ((u >> 16) & 1u)) >> 16;   // RNE
    return (unsigned short)u;
}
__device__ __forceinline__ float b2f(unsigned short u) {
    return __uint_as_float(((unsigned int)u) << 16);
}

// ---------------------------------------------------------------------------
// k_prep: blk 0..15   : Wd (512x128 f32) -> Wcat[0..512) bf16
//         blk 16..79  : Wcomb[d*128+o][e] = sum_h Wk[o][h]*Wd[d*128+h][e]
//         blk 80..904 : gather emb rows -> fp32 outs + bf16 Abf
// (byte-identical to rounds 5-9)
// ---------------------------------------------------------------------------
__global__ __launch_bounds__(256) void k_prep(const int* __restrict__ inp,
                                              const int* __restrict__ cand,
                                              const float* __restrict__ et,
                                              const float* __restrict__ Wd,
                                              const float* __restrict__ Ws,
                                              unsigned short* __restrict__ Wcat,
                                              unsigned short* __restrict__ Abf,
                                              float* __restrict__ o_emb,
                                              float* __restrict__ o_cemb) {
    int t = threadIdx.x;
    int blk = blockIdx.x;
    if (blk < 16) {
        const float4* src = (const float4*)Wd;
#pragma unroll
        for (int q = 0; q < 4; ++q) {
            int i = blk * 256 + t + q * 4096;   // 0..16383 float4s
            float4 v = src[i];
            ushort4 o;
            o.x = f2bf(v.x); o.y = f2bf(v.y); o.z = f2bf(v.z); o.w = f2bf(v.w);
            *(ushort4*)(Wcat + (size_t)i * 4) = o;
        }
        return;
    }
    if (blk < 80) {
        __shared__ __align__(16) float sdw[128 * 128];   // Wd_d tile [h][e]
        __shared__ float wk[8][128];
        int cb = blk - 16;                    // 0..63
        int d = cb >> 4, ot = cb & 15;
        const float4* src = (const float4*)(Wd + (size_t)d * 128 * 128);
#pragma unroll
        for (int q = 0; q < 16; ++q) {
            int i = t + q * 256;              // 4096 float4s
            *(float4*)(&sdw[i * 4]) = src[i];
        }
        for (int x = t; x < 8 * 128; x += 256) {
            int ol = x >> 7, h = x & 127;
            wk[ol][h] = Ws[(ot * 8 + ol) * 256 + 128 + h];
        }
        __syncthreads();
        int e = t & 127, og = t >> 7;
        float acc[4] = {0.f, 0.f, 0.f, 0.f};
        for (int h = 0; h < 128; ++h) {
            float rd = sdw[h * 128 + e];
#pragma unroll
            for (int k = 0; k < 4; ++k) acc[k] += rd * wk[og * 4 + k][h];
        }
#pragma unroll
        for (int k = 0; k < 4; ++k) {
            int o = ot * 8 + og * 4 + k;
            Wcat[(size_t)(512 + d * 128 + o) * 128 + e] = f2bf(acc[k]);
        }
        return;
    }
    // pregather: 825 blocks x 8 rows
    int pb = blk - 80;
    int r = pb * 8 + (t >> 5);                // 0..6599
    int fc = t & 31;
    int id = (r < NROWS_IN) ? inp[r] : cand[r - NROWS_IN];
    float4 v = *(const float4*)(et + (size_t)id * 128 + fc * 4);
    if (r < NROWS_IN) *(float4*)(o_emb + (size_t)r * 128 + fc * 4) = v;
    else              *(float4*)(o_cemb + (size_t)(r - NROWS_IN) * 128 + fc * 4) = v;
    ushort4 o;
    o.x = f2bf(v.x); o.y = f2bf(v.y); o.z = f2bf(v.z); o.w = f2bf(v.w);
    *(ushort4*)(Abf + (size_t)r * 128 + fc * 4) = o;
}

// ---------------------------------------------------------------------------
// k_mega (cooperative): blocks 0..127 = mid (round-8 body, phase 1);
// blocks 128..443 = cand GEMM (phase 1, cp tile kept in LDS) then score
// (phase 2, after grid.sync). Block 0 does the loss in phase 2.
// LDS 48.5 KB -> 3 blocks/CU -> capacity 768 >= 444 (co-residency ok).
// ---------------------------------------------------------------------------
__global__ __launch_bounds__(256, 2) void k_mega(const unsigned short* __restrict__ Abf,
                                                 const unsigned short* __restrict__ Wcat,
                                                 const float* __restrict__ Ws,
                                                 const float* __restrict__ bsc,
                                                 const float* __restrict__ wsc,
                                                 float* __restrict__ aggw,
                                                 float* __restrict__ apw,
                                                 float* __restrict__ o_ds,
                                                 float* __restrict__ o_dsc,
                                                 float* __restrict__ o_loss) {
    __shared__ __align__(16) char lds[49664];
    int bid = blockIdx.x;
    int t = threadIdx.x;

    if (bid < NBM) {
        // ======================= mid (phase 1) =======================
        unsigned short* sb   = (unsigned short*)lds;             // 128x128 bf16
        float*          skp  = (float*)lds;                      // 64x128 f32 overlay
        float*          sred = (float*)(lds + 32768);
        float*          sagg = (float*)(lds + 35328);
        float*          sap  = (float*)(lds + 35840);
        float*          spart= (float*)(lds + 36352);
        int b = bid >> 2, d = bid & 3;
        int w = t >> 6, lane = t & 63;
        int lr = lane & 31, g = lane >> 5;
        int rt = w & 1, ct = w >> 1;
        int arow = rt * 32 + lr;
        short8 a8[8];
        {
            const unsigned short* arp = Abf + (size_t)(b * SS + arow) * 128;
#pragma unroll
            for (int ks = 0; ks < 8; ++ks) {
                short8 v = {0, 0, 0, 0, 0, 0, 0, 0};
                if (arow < SS) v = *(const short8*)(arp + (ks * 2 + g) * 8);
                a8[ks] = v;
            }
        }
#pragma unroll
        for (int q = 0; q < 8; ++q) {
            int x = t + q * 256;
            int r = x >> 4, ch = x & 15;
            short8 v = *(const short8*)(Wcat + (size_t)(d * 128 + r) * 128 + ch * 8);
            *(short8*)(sb + r * 128 + ((ch ^ (r & 15)) << 3)) = v;
        }
        __syncthreads();
        int bcol0 = ct * 64 + lr, bcol1 = ct * 64 + 32 + lr;
        const unsigned short* pb0 = sb + bcol0 * 128;
        const unsigned short* pb1 = sb + bcol1 * 128;
        int b0x = bcol0 & 15, b1x = bcol1 & 15;
        f32x16 h0 = {}, h1 = {};
#pragma unroll
        for (int ks = 0; ks < 8; ++ks) {
            int chA = ks * 2 + g;
            short8 b8 = *(const short8*)(pb0 + ((chA ^ b0x) << 3));
            short8 c8 = *(const short8*)(pb1 + ((chA ^ b1x) << 3));
            h0 = __builtin_amdgcn_mfma_f32_32x32x16_bf16(a8[ks], b8, h0, 0, 0, 0);
            h1 = __builtin_amdgcn_mfma_f32_32x32x16_bf16(a8[ks], c8, h1, 0, 0, 0);
        }
        float p0 = 0.f, p1 = 0.f;
#pragma unroll
        for (int r = 0; r < 16; ++r) {
            int row = rt * 32 + (r & 3) + 8 * (r >> 2) + 4 * g;
            if (row < SS) { p0 += expf(h0[r]); p1 += expf(h1[r]); }
        }
        sred[bcol0 * 5 + rt * 2 + g] = p0;
        sred[bcol1 * 5 + rt * 2 + g] = p1;
        __syncthreads();
#pragma unroll
        for (int q = 0; q < 8; ++q) {
            int x = t + q * 256;
            int r = x >> 4, ch = x & 15;
            short8 v = *(const short8*)(Wcat + (size_t)(512 + d * 128 + r) * 128 + ch * 8);
            *(short8*)(sb + r * 128 + ((ch ^ (r & 15)) << 3)) = v;
        }
        if (t < 128) {
            float s = sred[t * 5] + sred[t * 5 + 1] + sred[t * 5 + 2] + sred[t * 5 + 3];
            float a = logf(s);
            sagg[t] = a;
            aggw[b * 512 + d * 128 + t] = a;
        }
        __syncthreads();
        f32x16 k0 = {}, k1 = {};
#pragma unroll
        for (int ks = 0; ks < 8; ++ks) {
            int chA = ks * 2 + g;
            short8 b8 = *(const short8*)(pb0 + ((chA ^ b0x) << 3));
            short8 c8 = *(const short8*)(pb1 + ((chA ^ b1x) << 3));
            k0 = __builtin_amdgcn_mfma_f32_32x32x16_bf16(a8[ks], b8, k0, 0, 0, 0);
            k1 = __builtin_amdgcn_mfma_f32_32x32x16_bf16(a8[ks], c8, k1, 0, 0, 0);
        }
        if (t < 128) {
            const float* wr = Ws + t * 256;
            float acc = bsc[t];
            for (int ch = 0; ch < 32; ++ch) {
                float4 a4 = *(const float4*)(sagg + ch * 4);
                float4 w4 = *(const float4*)(wr + ch * 4);
                acc += a4.x * w4.x + a4.y * w4.y + a4.z * w4.z + a4.w * w4.w;
            }
            sap[t] = acc;
            apw[(b * DDk + d) * 128 + t] = acc;
        }
        __syncthreads();
#pragma unroll
        for (int r = 0; r < 16; ++r) {
            int row = rt * 32 + (r & 3) + 8 * (r >> 2) + 4 * g;
            int c0 = ct * 64 + lr, c1 = ct * 64 + 32 + lr;
            skp[row * 128 + ((((c0 >> 2) ^ (row & 7)) << 2) | (c0 & 3))] = k0[r];
            skp[row * 128 + ((((c1 >> 2) ^ (row & 7)) << 2) | (c1 & 3))] = k1[r];
        }
        __syncthreads();
        if (t < 200) {
            int s = t >> 2, oq = t & 3;
            float acc = 0.f;
#pragma unroll
            for (int c = 0; c < 8; ++c) {
                int ch = oq * 8 + c;
                float4 a4 = *(const float4*)(sap + ch * 4);
                float4 w4 = *(const float4*)(wsc + ch * 4);
                float4 k4 = *(const float4*)(&skp[s * 128 + ((ch ^ (s & 7)) << 2)]);
                acc += w4.x * fmaxf(a4.x + k4.x, 0.f) + w4.y * fmaxf(a4.y + k4.y, 0.f)
                     + w4.z * fmaxf(a4.z + k4.z, 0.f) + w4.w * fmaxf(a4.w + k4.w, 0.f);
            }
            spart[t] = acc;
        }
        __syncthreads();
        if (t < SS) {
            float v = spart[t * 4] + spart[t * 4 + 1] + spart[t * 4 + 2] + spart[t * 4 + 3];
            o_ds[b * (DDk * SS) + d * SS + t] = v;
        }
    } else {
        // ======================= cand GEMM (phase 1) =======================
        unsigned short* sw    = (unsigned short*)lds;            // 128x128 bf16
        unsigned short* scp16 = (unsigned short*)(lds + 32768);  // 64x128 bf16 (persists)
        int j = bid - NBM;
        int tile = j >> 2, d = j & 3;
        int i0 = tile * 64;
        int w = t >> 6, lane = t & 63;
        int rbase = (w & 1) * 32, cbase = (w >> 1) * 64;
        int lr = lane & 31, g = lane >> 5;
        int arow = rbase + lr;
        short8 a8[8];
        {
            const unsigned short* arp = Abf + (size_t)(NROWS_IN + i0 + arow) * 128;
            bool valid = (i0 + arow < NI);
#pragma unroll
            for (int ks = 0; ks < 8; ++ks) {
                short8 v = {0, 0, 0, 0, 0, 0, 0, 0};
                if (valid) v = *(const short8*)(arp + (ks * 2 + g) * 8);
                a8[ks] = v;
            }
        }
#pragma unroll
        for (int q = 0; q < 8; ++q) {
            int x = t + q * 256;
            int r = x >> 4, ch = x & 15;
            short8 v = *(const short8*)(Wcat + (size_t)(512 + d * 128 + r) * 128 + ch * 8);
            *(short8*)(sw + r * 128 + ((ch ^ (r & 15)) << 3)) = v;
        }
        __syncthreads();
        int bcol0 = cbase + lr, bcol1 = cbase + 32 + lr;
        const unsigned short* pb0 = sw + bcol0 * 128;
        const unsigned short* pb1 = sw + bcol1 * 128;
        int b0x = bcol0 & 15, b1x = bcol1 & 15;
        f32x16 acc0 = {}, acc1 = {};
#pragma unroll
        for (int ks = 0; ks < 8; ++ks) {
            int chA = ks * 2 + g;
            short8 b8 = *(const short8*)(pb0 + ((chA ^ b0x) << 3));
            short8 c8 = *(const short8*)(pb1 + ((chA ^ b1x) << 3));
            acc0 = __builtin_amdgcn_mfma_f32_32x32x16_bf16(a8[ks], b8, acc0, 0, 0, 0);
            acc1 = __builtin_amdgcn_mfma_f32_32x32x16_bf16(a8[ks], c8, acc1, 0, 0, 0);
        }
        // scatter cp tile into scp16 (bf16, swizzled; separate region -> no barrier)
#pragma unroll
        for (int r = 0; r < 16; ++r) {
            int row = rbase + (r & 3) + 8 * (r >> 2) + 4 * g;
            int c0 = cbase + lr, c1 = cbase + 32 + lr;
            scp16[row * 128 + ((((c0 >> 2) ^ (row & 31)) << 2) | (c0 & 3))] = f2bf(acc0[r]);
            scp16[row * 128 + ((((c1 >> 2) ^ (row & 31)) << 2) | (c1 & 3))] = f2bf(acc1[r]);
        }
    }

    __syncthreads();
    __threadfence();                 // release our global writes (cross-XCD)
    cg::this_grid().sync();
    __threadfence();                 // acquire others' writes

    if (bid >= NBM) {
        // ======================= cand score (phase 2) =======================
        float*          sap2  = (float*)lds;                     // overlays dead sw
        float*          swv   = (float*)(lds + 16384);
        unsigned short* scp16 = (unsigned short*)(lds + 32768);  // from phase 1
        int j = bid - NBM;
        int tile = j >> 2, d = j & 3;
        int i0 = tile * 64;
        if (t < 128) swv[t] = wsc[t];
#pragma unroll
        for (int q = 0; q < 4; ++q) {
            int x = t + q * 256;                // 1024 float4s = 32x128 f32
            int b = x >> 5, ch = x & 31;
            float4 v = *(const float4*)(apw + (size_t)(b * 4 + d) * 128 + ch * 4);
            *(float4*)(&sap2[b * 128 + ((ch ^ (b & 7)) << 2)]) = v;
        }
        __syncthreads();
        int b2 = t >> 4, gg = t & 15;
        float accA0 = 0.f, accA1 = 0.f, accA2 = 0.f, accA3 = 0.f;
        float accB0 = 0.f, accB1 = 0.f, accB2 = 0.f, accB3 = 0.f;
        const float* sapA = sap2 + b2 * 128;
        const float* sapB = sap2 + (b2 + 16) * 128;
        int bx = b2 & 7;
        for (int ch = 0; ch < 32; ++ch) {
            float4 w4 = *(const float4*)(swv + ch * 4);
            float4 aA = *(const float4*)(sapA + ((ch ^ bx) << 2));
            float4 aB = *(const float4*)(sapB + ((ch ^ bx) << 2));
#pragma unroll
            for (int kk = 0; kk < 4; ++kk) {
                int il = kk * 16 + gg;
                ushort4 cc = *(const ushort4*)(scp16 + il * 128 + ((ch ^ (il & 31)) << 2));
                float c0 = b2f(cc.x), c1 = b2f(cc.y), c2 = b2f(cc.z), c3 = b2f(cc.w);
                float pA = w4.x * fmaxf(aA.x + c0, 0.f) + w4.y * fmaxf(aA.y + c1, 0.f)
                         + w4.z * fmaxf(aA.z + c2, 0.f) + w4.w * fmaxf(aA.w + c3, 0.f);
                float pB = w4.x * fmaxf(aB.x + c0, 0.f) + w4.y * fmaxf(aB.y + c1, 0.f)
                         + w4.z * fmaxf(aB.z + c2, 0.f) + w4.w * fmaxf(aB.w + c3, 0.f);
                if (kk == 0)      { accA0 += pA; accB0 += pB; }
                else if (kk == 1) { accA1 += pA; accB1 += pB; }
                else if (kk == 2) { accA2 += pA; accB2 += pB; }
                else              { accA3 += pA; accB3 += pB; }
            }
        }
        size_t baseA = (size_t)b2 * (DDk * NI) + d * NI;
        size_t baseB = (size_t)(b2 + 16) * (DDk * NI) + d * NI;
        int ia = i0 + gg;
        if (ia < NI)      { o_dsc[baseA + ia]      = accA0; o_dsc[baseB + ia]      = accB0; }
        if (ia + 16 < NI) { o_dsc[baseA + ia + 16] = accA1; o_dsc[baseB + ia + 16] = accB1; }
        if (ia + 32 < NI) { o_dsc[baseA + ia + 32] = accA2; o_dsc[baseB + ia + 32] = accB2; }
        if (ia + 48 < NI) { o_dsc[baseA + ia + 48] = accA3; o_dsc[baseB + ia + 48] = accB3; }
    } else if (bid == 0) {
        // ======================= loss (phase 2) =======================
        float* nrm = (float*)lds;
        if (t < 128) {
            const float* a = aggw + t * 128;
            float s = 0.f;
            for (int h = 0; h < 128; ++h) s += a[h] * a[h];
            nrm[t] = fmaxf(sqrtf(s), 1e-8f);
        }
        __syncthreads();
        float lb = 0.f;
        if (t < 32) {
            const float* a = aggw + t * 512;
            float i0 = 1.f / nrm[t * 4 + 0], i1 = 1.f / nrm[t * 4 + 1];
            float i2 = 1.f / nrm[t * 4 + 2], i3 = 1.f / nrm[t * 4 + 3];
            for (int h = 0; h < 128; ++h) {
                float u0 = a[h] * i0, u1 = a[128 + h] * i1;
                float u2 = a[256 + h] * i2, u3 = a[384 + h] * i3;
                float v = u0 + u1 + u2 + u3;
                lb += v * v - (u0 * u0 + u1 * u1 + u2 * u2 + u3 * u3);
            }
        }
        for (int off = 32; off; off >>= 1) lb += __shfl_down(lb, off);
        if (t == 0) o_loss[0] = lb / (float)(BB * DDk * (DDk - 1));
    }
}

// ---------------------------------------------------------------------------
extern "C" void kernel_launch(void* const* d_in, const int* in_sizes, int n_in,
                              void* d_out, int out_size, void* d_ws, size_t ws_size,
                              hipStream_t stream) {
    const int*   inp  = (const int*)d_in[0];
    const int*   cand = (const int*)d_in[1];
    const float* et   = (const float*)d_in[2];
    const float* Wd   = (const float*)d_in[3];
    const float* Ws   = (const float*)d_in[4];
    const float* bsc  = (const float*)d_in[5];
    const float* wsc  = (const float*)d_in[6];

    float* out = (float*)d_out;
    float* o_ds   = out;                  // (B,D,S)    6400
    float* o_dsc  = out + 6400;           // (B,D,I)    640000
    float* o_emb  = out + 646400;         // (B,S,E)    204800
    float* o_cemb = out + 851200;         // (I,E)      640000
    float* o_loss = out + 1491200;        // scalar

    char* wsb = (char*)d_ws;
    unsigned short* Wcat = (unsigned short*)wsb;              // 1024x128 bf16
    unsigned short* Abf  = (unsigned short*)(wsb + 262144);   // 6600x128 bf16
    float* aggw = (float*)(wsb + 2097152);                    // 16384 f32
    float* apw  = aggw + 16384;                               // 16384 f32

    hipLaunchKernelGGL(k_prep, dim3(905), dim3(256), 0, stream,
                       inp, cand, et, Wd, Ws, Wcat, Abf, o_emb, o_cemb);

    const unsigned short* AbfC  = Abf;
    const unsigned short* WcatC = Wcat;
    void* args[] = {(void*)&AbfC, (void*)&WcatC, (void*)&Ws, (void*)&bsc, (void*)&wsc,
                    (void*)&aggw, (void*)&apw, (void*)&o_ds, (void*)&o_dsc, (void*)&o_loss};
    hipLaunchCooperativeKernel((void*)k_mega, dim3(NBLK), dim3(256), args, 0, stream);
}

// Round 11
// 39.141 us; speedup vs baseline: 4.1505x; 4.1505x over previous
//
#include <hip/hip_runtime.h>

typedef __attribute__((ext_vector_type(8))) short short8;
typedef __attribute__((ext_vector_type(16))) float f32x16;

#define NROWS_IN 1600
#define NI 5000
#define BB 32
#define DDk 4
#define SS 50

__device__ __forceinline__ unsigned short f2bf(float f) {
    unsigned int u = __float_as_uint(f);
    u = (u + 0x7FFFu + ((u >> 16) & 1u)) >> 16;   // RNE
    return (unsigned short)u;
}
__device__ __forceinline__ float b2f(unsigned short u) {
    return __uint_as_float(((unsigned int)u) << 16);
}

// ---------------------------------------------------------------------------
// k_mid2: one block per (b,d), 128 blocks x 256 threads. No prep kernel:
//  - gather emb rows from et (f32) -> bf16 sa (+ o_emb when d==0)
//  - stage Wd_d (f32->bf16) -> sb ; MFMA1: hidden = emb @ Wd_d^T
//  - expsums from regs -> agg ; scatter hidden bf16 -> shid (overlays sa)
//  - restage sb <- Wk (f32->bf16) ; MFMA2: kp = hidden @ Wk^T  (reference form)
//  - ap -> demand_score ; aggw/apw to ws for k_cand2
// ---------------------------------------------------------------------------
__global__ __launch_bounds__(256) void k_mid2(const int* __restrict__ inp,
                                              const float* __restrict__ et,
                                              const float* __restrict__ Wd,
                                              const float* __restrict__ Ws,
                                              const float* __restrict__ bsc,
                                              const float* __restrict__ wsc,
                                              float* __restrict__ o_emb,
                                              float* __restrict__ aggw,
                                              float* __restrict__ apw,
                                              float* __restrict__ o_ds) {
    __shared__ __align__(16) char lds[53536];
    unsigned short* sa   = (unsigned short*)lds;             // 64x128 bf16 (16K)
    unsigned short* shid = (unsigned short*)lds;             // overlay of sa
    unsigned short* sb   = (unsigned short*)(lds + 16384);   // 128x128 bf16 (32K)
    float*          skp  = (float*)(lds + 16384);            // 64x128 f32 overlay
    float*          sred = (float*)(lds + 49152);            // 128x5
    float*          sagg = (float*)(lds + 51712);            // 128
    float*          sap  = (float*)(lds + 52224);            // 128
    float*          spart= (float*)(lds + 52736);            // 200

    int b = blockIdx.x >> 2, d = blockIdx.x & 3;
    int t = threadIdx.x;

    // stage sa: gather emb rows b*50..+50 (f32 -> bf16), zero-pad to 64
#pragma unroll
    for (int q = 0; q < 4; ++q) {
        int x = t + q * 256;
        int r = x >> 4, ch = x & 15;
        short8 v = {0, 0, 0, 0, 0, 0, 0, 0};
        if (r < SS) {
            int id = inp[b * SS + r];
            const float* p = et + (size_t)id * 128 + ch * 8;
            float4 v0 = *(const float4*)p;
            float4 v1 = *(const float4*)(p + 4);
            if (d == 0) {
                float* eo = o_emb + (size_t)(b * SS + r) * 128 + ch * 8;
                *(float4*)eo = v0; *(float4*)(eo + 4) = v1;
            }
            v[0] = (short)f2bf(v0.x); v[1] = (short)f2bf(v0.y);
            v[2] = (short)f2bf(v0.z); v[3] = (short)f2bf(v0.w);
            v[4] = (short)f2bf(v1.x); v[5] = (short)f2bf(v1.y);
            v[6] = (short)f2bf(v1.z); v[7] = (short)f2bf(v1.w);
        }
        *(short8*)(sa + r * 128 + ((ch ^ (r & 15)) << 3)) = v;
    }
    // stage sb: Wd_d (f32 -> bf16)
#pragma unroll
    for (int q = 0; q < 8; ++q) {
        int x = t + q * 256;
        int r = x >> 4, ch = x & 15;
        const float* p = Wd + (size_t)(d * 128 + r) * 128 + ch * 8;
        float4 v0 = *(const float4*)p;
        float4 v1 = *(const float4*)(p + 4);
        short8 v;
        v[0] = (short)f2bf(v0.x); v[1] = (short)f2bf(v0.y);
        v[2] = (short)f2bf(v0.z); v[3] = (short)f2bf(v0.w);
        v[4] = (short)f2bf(v1.x); v[5] = (short)f2bf(v1.y);
        v[6] = (short)f2bf(v1.z); v[7] = (short)f2bf(v1.w);
        *(short8*)(sb + r * 128 + ((ch ^ (r & 15)) << 3)) = v;
    }
    __syncthreads();

    int w = t >> 6, lane = t & 63;
    int lr = lane & 31, g = lane >> 5;
    int rt = w & 1, ct = w >> 1;
    int arow = rt * 32 + lr;
    int axor = arow & 15;
    int bcol0 = ct * 64 + lr, bcol1 = ct * 64 + 32 + lr;
    const unsigned short* pb0 = sb + bcol0 * 128;
    const unsigned short* pb1 = sb + bcol1 * 128;
    int b0x = bcol0 & 15, b1x = bcol1 & 15;
    // MFMA1: hidden
    f32x16 h0 = {}, h1 = {};
#pragma unroll
    for (int ks = 0; ks < 8; ++ks) {
        int chA = ks * 2 + g;
        short8 a8 = *(const short8*)(sa + arow * 128 + ((chA ^ axor) << 3));
        short8 b8 = *(const short8*)(pb0 + ((chA ^ b0x) << 3));
        short8 c8 = *(const short8*)(pb1 + ((chA ^ b1x) << 3));
        h0 = __builtin_amdgcn_mfma_f32_32x32x16_bf16(a8, b8, h0, 0, 0, 0);
        h1 = __builtin_amdgcn_mfma_f32_32x32x16_bf16(a8, c8, h1, 0, 0, 0);
    }
    // exp partial sums over valid rows
    float p0 = 0.f, p1 = 0.f;
#pragma unroll
    for (int r = 0; r < 16; ++r) {
        int row = rt * 32 + (r & 3) + 8 * (r >> 2) + 4 * g;
        if (row < SS) { p0 += expf(h0[r]); p1 += expf(h1[r]); }
    }
    sred[bcol0 * 5 + rt * 2 + g] = p0;
    sred[bcol1 * 5 + rt * 2 + g] = p1;
    __syncthreads();          // sa reads done; sred ready
    // scatter hidden (bf16) -> shid (overlays sa)
#pragma unroll
    for (int r = 0; r < 16; ++r) {
        int row = rt * 32 + (r & 3) + 8 * (r >> 2) + 4 * g;
        int c0 = ct * 64 + lr, c1 = ct * 64 + 32 + lr;
        shid[row * 128 + ((((c0 >> 3) ^ (row & 15)) << 3) | (c0 & 7))] = f2bf(h0[r]);
        shid[row * 128 + ((((c1 >> 3) ^ (row & 15)) << 3) | (c1 & 7))] = f2bf(h1[r]);
    }
    // restage sb <- Wk (Ws second half, f32 -> bf16); agg concurrently
#pragma unroll
    for (int q = 0; q < 8; ++q) {
        int x = t + q * 256;
        int r = x >> 4, ch = x & 15;
        const float* p = Ws + (size_t)r * 256 + 128 + ch * 8;
        float4 v0 = *(const float4*)p;
        float4 v1 = *(const float4*)(p + 4);
        short8 v;
        v[0] = (short)f2bf(v0.x); v[1] = (short)f2bf(v0.y);
        v[2] = (short)f2bf(v0.z); v[3] = (short)f2bf(v0.w);
        v[4] = (short)f2bf(v1.x); v[5] = (short)f2bf(v1.y);
        v[6] = (short)f2bf(v1.z); v[7] = (short)f2bf(v1.w);
        *(short8*)(sb + r * 128 + ((ch ^ (r & 15)) << 3)) = v;
    }
    if (t < 128) {
        float s = sred[t * 5] + sred[t * 5 + 1] + sred[t * 5 + 2] + sred[t * 5 + 3];
        float a = logf(s);
        sagg[t] = a;
        aggw[b * 512 + d * 128 + t] = a;
    }
    __syncthreads();          // shid, sb(Wk), sagg ready
    // MFMA2: kp = hidden @ Wk^T
    f32x16 k0 = {}, k1 = {};
#pragma unroll
    for (int ks = 0; ks < 8; ++ks) {
        int chA = ks * 2 + g;
        short8 a8 = *(const short8*)(shid + arow * 128 + ((chA ^ axor) << 3));
        short8 b8 = *(const short8*)(pb0 + ((chA ^ b0x) << 3));
        short8 c8 = *(const short8*)(pb1 + ((chA ^ b1x) << 3));
        k0 = __builtin_amdgcn_mfma_f32_32x32x16_bf16(a8, b8, k0, 0, 0, 0);
        k1 = __builtin_amdgcn_mfma_f32_32x32x16_bf16(a8, c8, k1, 0, 0, 0);
    }
    // ap (t<128): sagg . Ws(first half) + bsc
    if (t < 128) {
        const float* wr = Ws + t * 256;
        float acc = bsc[t];
        for (int ch = 0; ch < 32; ++ch) {
            float4 a4 = *(const float4*)(sagg + ch * 4);
            float4 w4 = *(const float4*)(wr + ch * 4);
            acc += a4.x * w4.x + a4.y * w4.y + a4.z * w4.z + a4.w * w4.w;
        }
        sap[t] = acc;
        apw[(b * DDk + d) * 128 + t] = acc;
    }
    __syncthreads();          // sb reads done; sap ready
    // scatter kp -> skp (swizzled f32, overlays sb)
#pragma unroll
    for (int r = 0; r < 16; ++r) {
        int row = rt * 32 + (r & 3) + 8 * (r >> 2) + 4 * g;
        int c0 = ct * 64 + lr, c1 = ct * 64 + 32 + lr;
        skp[row * 128 + ((((c0 >> 2) ^ (row & 7)) << 2) | (c0 & 3))] = k0[r];
        skp[row * 128 + ((((c1 >> 2) ^ (row & 7)) << 2) | (c1 & 3))] = k1[r];
    }
    __syncthreads();
    // score: thread (s = t>>2, oq = t&3) -> 32-o partial
    if (t < 200) {
        int s = t >> 2, oq = t & 3;
        float acc = 0.f;
#pragma unroll
        for (int c = 0; c < 8; ++c) {
            int ch = oq * 8 + c;
            float4 a4 = *(const float4*)(sap + ch * 4);
            float4 w4 = *(const float4*)(wsc + ch * 4);
            float4 k4 = *(const float4*)(&skp[s * 128 + ((ch ^ (s & 7)) << 2)]);
            acc += w4.x * fmaxf(a4.x + k4.x, 0.f) + w4.y * fmaxf(a4.y + k4.y, 0.f)
                 + w4.z * fmaxf(a4.z + k4.z, 0.f) + w4.w * fmaxf(a4.w + k4.w, 0.f);
        }
        spart[t] = acc;
    }
    __syncthreads();
    if (t < SS) {
        float v = spart[t * 4] + spart[t * 4 + 1] + spart[t * 4 + 2] + spart[t * 4 + 3];
        o_ds[b * (DDk * SS) + d * SS + t] = v;
    }
}

// ---------------------------------------------------------------------------
// k_cand2: blocks 0..315 (64-i tile, d): gather cand emb -> MFMA1 hidden ->
// shid -> MFMA2 cp = hidden @ Wk^T -> scp16 -> relu score (ap from apw).
// block 316: demand_sim_loss from aggw.
// ---------------------------------------------------------------------------
__global__ __launch_bounds__(256) void k_cand2(const int* __restrict__ cand,
                                               const float* __restrict__ et,
                                               const float* __restrict__ Wd,
                                               const float* __restrict__ Ws,
                                               const float* __restrict__ apw,
                                               const float* __restrict__ aggw,
                                               const float* __restrict__ wsc,
                                               float* __restrict__ o_cemb,
                                               float* __restrict__ o_dsc,
                                               float* __restrict__ o_loss) {
    __shared__ __align__(16) char lds[66048];
    int gid = blockIdx.x;
    int t = threadIdx.x;
    if (gid >= 316) {                       // ---- loss block ----
        float* nrm = (float*)lds;
        if (t < 128) {
            const float* a = aggw + t * 128;
            float s = 0.f;
            for (int h = 0; h < 128; ++h) s += a[h] * a[h];
            nrm[t] = fmaxf(sqrtf(s), 1e-8f);
        }
        __syncthreads();
        float lb = 0.f;
        if (t < 32) {
            const float* a = aggw + t * 512;
            float i0 = 1.f / nrm[t * 4 + 0], i1 = 1.f / nrm[t * 4 + 1];
            float i2 = 1.f / nrm[t * 4 + 2], i3 = 1.f / nrm[t * 4 + 3];
            for (int h = 0; h < 128; ++h) {
                float u0 = a[h] * i0, u1 = a[128 + h] * i1;
                float u2 = a[256 + h] * i2, u3 = a[384 + h] * i3;
                float v = u0 + u1 + u2 + u3;
                lb += v * v - (u0 * u0 + u1 * u1 + u2 * u2 + u3 * u3);
            }
        }
        for (int off = 32; off; off >>= 1) lb += __shfl_down(lb, off);
        if (t == 0) o_loss[0] = lb / (float)(BB * DDk * (DDk - 1));
        return;
    }
    unsigned short* sa    = (unsigned short*)lds;              // 64x128 bf16 (16K)
    unsigned short* shid  = (unsigned short*)lds;              // overlay of sa
    unsigned short* sb    = (unsigned short*)(lds + 16384);    // 128x128 bf16 (32K)
    unsigned short* scp16 = (unsigned short*)(lds + 16384);    // 64x128 bf16 overlay
    float*          sap   = (float*)(lds + 49152);             // 32x128 f32 (16K)
    float*          swv   = (float*)(lds + 65536);             // 128 f32

    int tile = gid >> 2, d = gid & 3;
    int i0 = tile * 64;
    // stage sa: gather cand rows (f32 -> bf16), zero-pad; o_cemb when d==0
#pragma unroll
    for (int q = 0; q < 4; ++q) {
        int x = t + q * 256;
        int r = x >> 4, ch = x & 15;
        short8 v = {0, 0, 0, 0, 0, 0, 0, 0};
        if (i0 + r < NI) {
            int id = cand[i0 + r];
            const float* p = et + (size_t)id * 128 + ch * 8;
            float4 v0 = *(const float4*)p;
            float4 v1 = *(const float4*)(p + 4);
            if (d == 0) {
                float* eo = o_cemb + (size_t)(i0 + r) * 128 + ch * 8;
                *(float4*)eo = v0; *(float4*)(eo + 4) = v1;
            }
            v[0] = (short)f2bf(v0.x); v[1] = (short)f2bf(v0.y);
            v[2] = (short)f2bf(v0.z); v[3] = (short)f2bf(v0.w);
            v[4] = (short)f2bf(v1.x); v[5] = (short)f2bf(v1.y);
            v[6] = (short)f2bf(v1.z); v[7] = (short)f2bf(v1.w);
        }
        *(short8*)(sa + r * 128 + ((ch ^ (r & 15)) << 3)) = v;
    }
    // stage sb: Wd_d (f32 -> bf16)
#pragma unroll
    for (int q = 0; q < 8; ++q) {
        int x = t + q * 256;
        int r = x >> 4, ch = x & 15;
        const float* p = Wd + (size_t)(d * 128 + r) * 128 + ch * 8;
        float4 v0 = *(const float4*)p;
        float4 v1 = *(const float4*)(p + 4);
        short8 v;
        v[0] = (short)f2bf(v0.x); v[1] = (short)f2bf(v0.y);
        v[2] = (short)f2bf(v0.z); v[3] = (short)f2bf(v0.w);
        v[4] = (short)f2bf(v1.x); v[5] = (short)f2bf(v1.y);
        v[6] = (short)f2bf(v1.z); v[7] = (short)f2bf(v1.w);
        *(short8*)(sb + r * 128 + ((ch ^ (r & 15)) << 3)) = v;
    }
    // stage sap (ap rows for this d) + swv
    if (t < 128) swv[t] = wsc[t];
#pragma unroll
    for (int q = 0; q < 4; ++q) {
        int x = t + q * 256;                // 1024 float4s = 32x128 f32
        int b = x >> 5, ch = x & 31;
        float4 v = *(const float4*)(apw + (size_t)(b * 4 + d) * 128 + ch * 4);
        *(float4*)(&sap[b * 128 + ((ch ^ (b & 7)) << 2)]) = v;
    }
    __syncthreads();

    int w = t >> 6, lane = t & 63;
    int rbase = (w & 1) * 32, cbase = (w >> 1) * 64;
    int lr = lane & 31, g = lane >> 5;
    int arow = rbase + lr;
    int axor = arow & 15;
    int bcol0 = cbase + lr, bcol1 = cbase + 32 + lr;
    const unsigned short* pb0 = sb + bcol0 * 128;
    const unsigned short* pb1 = sb + bcol1 * 128;
    int b0x = bcol0 & 15, b1x = bcol1 & 15;
    // MFMA1: cand_hidden
    f32x16 h0 = {}, h1 = {};
#pragma unroll
    for (int ks = 0; ks < 8; ++ks) {
        int chA = ks * 2 + g;
        short8 a8 = *(const short8*)(sa + arow * 128 + ((chA ^ axor) << 3));
        short8 b8 = *(const short8*)(pb0 + ((chA ^ b0x) << 3));
        short8 c8 = *(const short8*)(pb1 + ((chA ^ b1x) << 3));
        h0 = __builtin_amdgcn_mfma_f32_32x32x16_bf16(a8, b8, h0, 0, 0, 0);
        h1 = __builtin_amdgcn_mfma_f32_32x32x16_bf16(a8, c8, h1, 0, 0, 0);
    }
    __syncthreads();          // sa reads done
    // scatter hidden bf16 -> shid; restage sb <- Wk
#pragma unroll
    for (int r = 0; r < 16; ++r) {
        int row = rbase + (r & 3) + 8 * (r >> 2) + 4 * g;
        int c0 = cbase + lr, c1 = cbase + 32 + lr;
        shid[row * 128 + ((((c0 >> 3) ^ (row & 15)) << 3) | (c0 & 7))] = f2bf(h0[r]);
        shid[row * 128 + ((((c1 >> 3) ^ (row & 15)) << 3) | (c1 & 7))] = f2bf(h1[r]);
    }
#pragma unroll
    for (int q = 0; q < 8; ++q) {
        int x = t + q * 256;
        int r = x >> 4, ch = x & 15;
        const float* p = Ws + (size_t)r * 256 + 128 + ch * 8;
        float4 v0 = *(const float4*)p;
        float4 v1 = *(const float4*)(p + 4);
        short8 v;
        v[0] = (short)f2bf(v0.x); v[1] = (short)f2bf(v0.y);
        v[2] = (short)f2bf(v0.z); v[3] = (short)f2bf(v0.w);
        v[4] = (short)f2bf(v1.x); v[5] = (short)f2bf(v1.y);
        v[6] = (short)f2bf(v1.z); v[7] = (short)f2bf(v1.w);
        *(short8*)(sb + r * 128 + ((ch ^ (r & 15)) << 3)) = v;
    }
    __syncthreads();          // shid + sb(Wk) ready
    // MFMA2: cp = hidden @ Wk^T
    f32x16 acc0 = {}, acc1 = {};
#pragma unroll
    for (int ks = 0; ks < 8; ++ks) {
        int chA = ks * 2 + g;
        short8 a8 = *(const short8*)(shid + arow * 128 + ((chA ^ axor) << 3));
        short8 b8 = *(const short8*)(pb0 + ((chA ^ b0x) << 3));
        short8 c8 = *(const short8*)(pb1 + ((chA ^ b1x) << 3));
        acc0 = __builtin_amdgcn_mfma_f32_32x32x16_bf16(a8, b8, acc0, 0, 0, 0);
        acc1 = __builtin_amdgcn_mfma_f32_32x32x16_bf16(a8, c8, acc1, 0, 0, 0);
    }
    __syncthreads();          // sb reads done
    // scatter cp tile into scp16 (bf16, swizzled; overlays sb)
#pragma unroll
    for (int r = 0; r < 16; ++r) {
        int row = rbase + (r & 3) + 8 * (r >> 2) + 4 * g;
        int c0 = cbase + lr, c1 = cbase + 32 + lr;
        scp16[row * 128 + ((((c0 >> 2) ^ (row & 31)) << 2) | (c0 & 3))] = f2bf(acc0[r]);
        scp16[row * 128 + ((((c1 >> 2) ^ (row & 31)) << 2) | (c1 & 3))] = f2bf(acc1[r]);
    }
    __syncthreads();
    // score: thread owns b in {b2, b2+16} x 4 i's (i = i0 + kk*16 + gg)
    int b2 = t >> 4, gg = t & 15;
    float accA0 = 0.f, accA1 = 0.f, accA2 = 0.f, accA3 = 0.f;
    float accB0 = 0.f, accB1 = 0.f, accB2 = 0.f, accB3 = 0.f;
    const float* sapA = sap + b2 * 128;
    const float* sapB = sap + (b2 + 16) * 128;
    int bx = b2 & 7;
    for (int ch = 0; ch < 32; ++ch) {
        float4 w4 = *(const float4*)(swv + ch * 4);
        float4 aA = *(const float4*)(sapA + ((ch ^ bx) << 2));
        float4 aB = *(const float4*)(sapB + ((ch ^ bx) << 2));
#pragma unroll
        for (int kk = 0; kk < 4; ++kk) {
            int il = kk * 16 + gg;
            ushort4 cc = *(const ushort4*)(scp16 + il * 128 + ((ch ^ (il & 31)) << 2));
            float c0 = b2f(cc.x), c1 = b2f(cc.y), c2 = b2f(cc.z), c3 = b2f(cc.w);
            float pA = w4.x * fmaxf(aA.x + c0, 0.f) + w4.y * fmaxf(aA.y + c1, 0.f)
                     + w4.z * fmaxf(aA.z + c2, 0.f) + w4.w * fmaxf(aA.w + c3, 0.f);
            float pB = w4.x * fmaxf(aB.x + c0, 0.f) + w4.y * fmaxf(aB.y + c1, 0.f)
                     + w4.z * fmaxf(aB.z + c2, 0.f) + w4.w * fmaxf(aB.w + c3, 0.f);
            if (kk == 0)      { accA0 += pA; accB0 += pB; }
            else if (kk == 1) { accA1 += pA; accB1 += pB; }
            else if (kk == 2) { accA2 += pA; accB2 += pB; }
            else              { accA3 += pA; accB3 += pB; }
        }
    }
    {
        size_t baseA = (size_t)b2 * (DDk * NI) + d * NI;
        size_t baseB = (size_t)(b2 + 16) * (DDk * NI) + d * NI;
        int ia = i0 + gg;
        if (ia < NI)      { o_dsc[baseA + ia]      = accA0; o_dsc[baseB + ia]      = accB0; }
        if (ia + 16 < NI) { o_dsc[baseA + ia + 16] = accA1; o_dsc[baseB + ia + 16] = accB1; }
        if (ia + 32 < NI) { o_dsc[baseA + ia + 32] = accA2; o_dsc[baseB + ia + 32] = accB2; }
        if (ia + 48 < NI) { o_dsc[baseA + ia + 48] = accA3; o_dsc[baseB + ia + 48] = accB3; }
    }
}

// ---------------------------------------------------------------------------
extern "C" void kernel_launch(void* const* d_in, const int* in_sizes, int n_in,
                              void* d_out, int out_size, void* d_ws, size_t ws_size,
                              hipStream_t stream) {
    const int*   inp  = (const int*)d_in[0];
    const int*   cand = (const int*)d_in[1];
    const float* et   = (const float*)d_in[2];
    const float* Wd   = (const float*)d_in[3];
    const float* Ws   = (const float*)d_in[4];
    const float* bsc  = (const float*)d_in[5];
    const float* wsc  = (const float*)d_in[6];

    float* out = (float*)d_out;
    float* o_ds   = out;                  // (B,D,S)    6400
    float* o_dsc  = out + 6400;           // (B,D,I)    640000
    float* o_emb  = out + 646400;         // (B,S,E)    204800
    float* o_cemb = out + 851200;         // (I,E)      640000
    float* o_loss = out + 1491200;        // scalar

    float* ws   = (float*)d_ws;
    float* aggw = ws;                     // 16384 f32
    float* apw  = ws + 16384;             // 16384 f32

    hipLaunchKernelGGL(k_mid2, dim3(128), dim3(256), 0, stream,
                       inp, et, Wd, Ws, bsc, wsc, o_emb, aggw, apw, o_ds);
    hipLaunchKernelGGL(k_cand2, dim3(317), dim3(256), 0, stream,
                       cand, et, Wd, Ws, apw, aggw, wsc, o_cemb, o_dsc, o_loss);
}

// Round 12
// 37.075 us; speedup vs baseline: 4.3818x; 1.0557x over previous
//
#include <hip/hip_runtime.h>

typedef __attribute__((ext_vector_type(8))) short short8;
typedef __attribute__((ext_vector_type(16))) float f32x16;

#define NROWS_IN 1600
#define NI 5000
#define BB 32
#define DDk 4
#define SS 50

__device__ __forceinline__ unsigned short f2bf(float f) {
    unsigned int u = __float_as_uint(f);
    u = (u + 0x7FFFu + ((u >> 16) & 1u)) >> 16;   // RNE
    return (unsigned short)u;
}
__device__ __forceinline__ float b2f(unsigned short u) {
    return __uint_as_float(((unsigned int)u) << 16);
}

// ---------------------------------------------------------------------------
// k_prep: blk 0..15   : Wd (512x128 f32) -> Wcat[0..512) bf16
//         blk 16..79  : Wcomb[d*128+o][e] = sum_h Wk[o][h]*Wd[d*128+h][e]
//                       (Wd_d tile staged in LDS) -> Wcat[512..1024) bf16
//         blk 80..904 : gather emb rows (input then cand) -> fp32 outs + bf16 Abf
// ---------------------------------------------------------------------------
__global__ __launch_bounds__(256) void k_prep(const int* __restrict__ inp,
                                              const int* __restrict__ cand,
                                              const float* __restrict__ et,
                                              const float* __restrict__ Wd,
                                              const float* __restrict__ Ws,
                                              unsigned short* __restrict__ Wcat,
                                              unsigned short* __restrict__ Abf,
                                              float* __restrict__ o_emb,
                                              float* __restrict__ o_cemb) {
    int t = threadIdx.x;
    int blk = blockIdx.x;
    if (blk < 16) {
        const float4* src = (const float4*)Wd;
#pragma unroll
        for (int q = 0; q < 4; ++q) {
            int i = blk * 256 + t + q * 4096;   // 0..16383 float4s
            float4 v = src[i];
            ushort4 o;
            o.x = f2bf(v.x); o.y = f2bf(v.y); o.z = f2bf(v.z); o.w = f2bf(v.w);
            *(ushort4*)(Wcat + (size_t)i * 4) = o;
        }
        return;
    }
    if (blk < 80) {
        __shared__ __align__(16) float sdw[128 * 128];   // Wd_d tile [h][e]
        __shared__ float wk[8][128];
        int cb = blk - 16;                    // 0..63
        int d = cb >> 4, ot = cb & 15;
        const float4* src = (const float4*)(Wd + (size_t)d * 128 * 128);
#pragma unroll
        for (int q = 0; q < 16; ++q) {
            int i = t + q * 256;              // 4096 float4s
            *(float4*)(&sdw[i * 4]) = src[i];
        }
        for (int x = t; x < 8 * 128; x += 256) {
            int ol = x >> 7, h = x & 127;
            wk[ol][h] = Ws[(ot * 8 + ol) * 256 + 128 + h];
        }
        __syncthreads();
        int e = t & 127, og = t >> 7;
        float acc[4] = {0.f, 0.f, 0.f, 0.f};
        for (int h = 0; h < 128; ++h) {
            float rd = sdw[h * 128 + e];
#pragma unroll
            for (int k = 0; k < 4; ++k) acc[k] += rd * wk[og * 4 + k][h];
        }
#pragma unroll
        for (int k = 0; k < 4; ++k) {
            int o = ot * 8 + og * 4 + k;
            Wcat[(size_t)(512 + d * 128 + o) * 128 + e] = f2bf(acc[k]);
        }
        return;
    }
    // pregather: 825 blocks x 8 rows
    int pb = blk - 80;
    int r = pb * 8 + (t >> 5);                // 0..6599
    int fc = t & 31;
    int id = (r < NROWS_IN) ? inp[r] : cand[r - NROWS_IN];
    float4 v = *(const float4*)(et + (size_t)id * 128 + fc * 4);
    if (r < NROWS_IN) *(float4*)(o_emb + (size_t)r * 128 + fc * 4) = v;
    else              *(float4*)(o_cemb + (size_t)(r - NROWS_IN) * 128 + fc * 4) = v;
    ushort4 o;
    o.x = f2bf(v.x); o.y = f2bf(v.y); o.z = f2bf(v.z); o.w = f2bf(v.w);
    *(ushort4*)(Abf + (size_t)r * 128 + fc * 4) = o;
}

// ---------------------------------------------------------------------------
// k_fused_mid: one block per (b,d), 128 blocks x 256 threads.
//   MFMA1: hidden[s][h] = emb[b,s,:] @ Wd_d^T       (exp-sums from regs)
//   MFMA2: kp[s][o]     = emb[b,s,:] @ Wcomb_d^T    (scattered to LDS)
//   agg -> ap -> demand_score, all in-block. No hidden/kp global round-trip.
// LDS: [sa 16K][sb 32K][sred 2.5K][sagg][sap][spart]; skp(32K) overlays sa+sb
// after both MFMAs.
// ---------------------------------------------------------------------------
__global__ __launch_bounds__(256) void k_fused_mid(const unsigned short* __restrict__ Abf,
                                                   const unsigned short* __restrict__ Wcat,
                                                   const float* __restrict__ Ws,
                                                   const float* __restrict__ bsc,
                                                   const float* __restrict__ wsc,
                                                   float* __restrict__ aggw,
                                                   float* __restrict__ apw,
                                                   float* __restrict__ o_ds) {
    __shared__ __align__(16) char lds[53536];
    unsigned short* sa   = (unsigned short*)lds;             // 64x128 bf16
    unsigned short* sb   = (unsigned short*)(lds + 16384);   // 128x128 bf16
    float*          skp  = (float*)lds;                      // 64x128 f32 (overlay)
    float*          sred = (float*)(lds + 49152);            // 128x5
    float*          sagg = (float*)(lds + 51712);            // 128
    float*          sap  = (float*)(lds + 52224);            // 128
    float*          spart= (float*)(lds + 52736);            // 200

    int b = blockIdx.x >> 2, d = blockIdx.x & 3;
    int t = threadIdx.x;
    // stage sa: emb rows b*50..+50, zero-pad to 64
#pragma unroll
    for (int q = 0; q < 4; ++q) {
        int x = t + q * 256;
        int r = x >> 4, ch = x & 15;
        short8 v = {0, 0, 0, 0, 0, 0, 0, 0};
        if (r < SS) v = *(const short8*)(Abf + (size_t)(b * SS + r) * 128 + ch * 8);
        *(short8*)(sa + r * 128 + ((ch ^ (r & 15)) << 3)) = v;
    }
    // stage sb: Wd_d = Wcat rows d*128..+128
#pragma unroll
    for (int q = 0; q < 8; ++q) {
        int x = t + q * 256;
        int r = x >> 4, ch = x & 15;
        short8 v = *(const short8*)(Wcat + (size_t)(d * 128 + r) * 128 + ch * 8);
        *(short8*)(sb + r * 128 + ((ch ^ (r & 15)) << 3)) = v;
    }
    __syncthreads();

    int w = t >> 6, lane = t & 63;
    int lr = lane & 31, g = lane >> 5;
    int rt = w & 1, ct = w >> 1;
    int arow = rt * 32 + lr;
    int bcol0 = ct * 64 + lr, bcol1 = ct * 64 + 32 + lr;
    const unsigned short* pa  = sa + arow * 128;
    const unsigned short* pb0 = sb + bcol0 * 128;
    const unsigned short* pb1 = sb + bcol1 * 128;
    int axor = arow & 15, b0x = bcol0 & 15, b1x = bcol1 & 15;
    // MFMA1: hidden
    f32x16 h0 = {}, h1 = {};
#pragma unroll
    for (int ks = 0; ks < 8; ++ks) {
        int chA = ks * 2 + g;
        short8 a8 = *(const short8*)(pa  + ((chA ^ axor) << 3));
        short8 b8 = *(const short8*)(pb0 + ((chA ^ b0x) << 3));
        short8 c8 = *(const short8*)(pb1 + ((chA ^ b1x) << 3));
        h0 = __builtin_amdgcn_mfma_f32_32x32x16_bf16(a8, b8, h0, 0, 0, 0);
        h1 = __builtin_amdgcn_mfma_f32_32x32x16_bf16(a8, c8, h1, 0, 0, 0);
    }
    // exp partial sums over valid rows (s < 50), per output col
    float p0 = 0.f, p1 = 0.f;
#pragma unroll
    for (int r = 0; r < 16; ++r) {
        int row = rt * 32 + (r & 3) + 8 * (r >> 2) + 4 * g;
        if (row < SS) { p0 += expf(h0[r]); p1 += expf(h1[r]); }
    }
    sred[bcol0 * 5 + rt * 2 + g] = p0;
    sred[bcol1 * 5 + rt * 2 + g] = p1;
    __syncthreads();
    // restage sb <- Wcomb_d (Wcat rows 512+d*128..+128); agg concurrently
#pragma unroll
    for (int q = 0; q < 8; ++q) {
        int x = t + q * 256;
        int r = x >> 4, ch = x & 15;
        short8 v = *(const short8*)(Wcat + (size_t)(512 + d * 128 + r) * 128 + ch * 8);
        *(short8*)(sb + r * 128 + ((ch ^ (r & 15)) << 3)) = v;
    }
    if (t < 128) {
        float s = sred[t * 5] + sred[t * 5 + 1] + sred[t * 5 + 2] + sred[t * 5 + 3];
        float a = logf(s);
        sagg[t] = a;
        aggw[b * 512 + d * 128 + t] = a;
    }
    __syncthreads();
    // MFMA2: kp
    f32x16 k0 = {}, k1 = {};
#pragma unroll
    for (int ks = 0; ks < 8; ++ks) {
        int chA = ks * 2 + g;
        short8 a8 = *(const short8*)(pa  + ((chA ^ axor) << 3));
        short8 b8 = *(const short8*)(pb0 + ((chA ^ b0x) << 3));
        short8 c8 = *(const short8*)(pb1 + ((chA ^ b1x) << 3));
        k0 = __builtin_amdgcn_mfma_f32_32x32x16_bf16(a8, b8, k0, 0, 0, 0);
        k1 = __builtin_amdgcn_mfma_f32_32x32x16_bf16(a8, c8, k1, 0, 0, 0);
    }
    // ap (reads sagg + global Ws; writes sap) — independent of MFMA2 operands
    if (t < 128) {
        const float* wr = Ws + t * 256;
        float acc = bsc[t];
        for (int ch = 0; ch < 32; ++ch) {
            float4 a4 = *(const float4*)(sagg + ch * 4);
            float4 w4 = *(const float4*)(wr + ch * 4);
            acc += a4.x * w4.x + a4.y * w4.y + a4.z * w4.z + a4.w * w4.w;
        }
        sap[t] = acc;
        apw[(b * DDk + d) * 128 + t] = acc;
    }
    __syncthreads();   // all waves done reading sa/sb; sap ready
    // scatter kp -> skp (swizzled f32, overlays sa + first half of sb)
#pragma unroll
    for (int r = 0; r < 16; ++r) {
        int row = rt * 32 + (r & 3) + 8 * (r >> 2) + 4 * g;
        int c0 = ct * 64 + lr, c1 = ct * 64 + 32 + lr;
        skp[row * 128 + ((((c0 >> 2) ^ (row & 7)) << 2) | (c0 & 3))] = k0[r];
        skp[row * 128 + ((((c1 >> 2) ^ (row & 7)) << 2) | (c1 & 3))] = k1[r];
    }
    __syncthreads();
    // score: thread (s = t>>2, oq = t&3) -> 32-o partial
    if (t < 200) {
        int s = t >> 2, oq = t & 3;
        float acc = 0.f;
#pragma unroll
        for (int c = 0; c < 8; ++c) {
            int ch = oq * 8 + c;
            float4 a4 = *(const float4*)(sap + ch * 4);
            float4 w4 = *(const float4*)(wsc + ch * 4);
            float4 k4 = *(const float4*)(&skp[s * 128 + ((ch ^ (s & 7)) << 2)]);
            acc += w4.x * fmaxf(a4.x + k4.x, 0.f) + w4.y * fmaxf(a4.y + k4.y, 0.f)
                 + w4.z * fmaxf(a4.z + k4.z, 0.f) + w4.w * fmaxf(a4.w + k4.w, 0.f);
        }
        spart[t] = acc;
    }
    __syncthreads();
    if (t < SS) {
        float v = spart[t * 4] + spart[t * 4 + 1] + spart[t * 4 + 2] + spart[t * 4 + 3];
        o_ds[b * (DDk * SS) + d * SS + t] = v;
    }
}

// ---------------------------------------------------------------------------
// k_cand: blocks 0..315: (64-i tile, d): MFMA cand GEMM -> LDS -> relu score.
//         block 316: demand_sim_loss from aggw.
// ---------------------------------------------------------------------------
__global__ __launch_bounds__(256) void k_cand(const unsigned short* __restrict__ Abf,
                                              const unsigned short* __restrict__ Wcat,
                                              const float* __restrict__ apw,
                                              const float* __restrict__ aggw,
                                              const float* __restrict__ wsc,
                                              float* __restrict__ o_dsc,
                                              float* __restrict__ o_loss) {
    __shared__ __align__(16) char lds[66048];
    int gid = blockIdx.x;
    int t = threadIdx.x;
    if (gid >= 316) {                       // ---- loss block ----
        float* nrm = (float*)lds;           // 128 floats
        if (t < 128) {
            const float* a = aggw + t * 128;
            float s = 0.f;
            for (int h = 0; h < 128; ++h) s += a[h] * a[h];
            nrm[t] = fmaxf(sqrtf(s), 1e-8f);
        }
        __syncthreads();
        float lb = 0.f;
        if (t < 32) {
            const float* a = aggw + t * 512;
            float i0 = 1.f / nrm[t * 4 + 0], i1 = 1.f / nrm[t * 4 + 1];
            float i2 = 1.f / nrm[t * 4 + 2], i3 = 1.f / nrm[t * 4 + 3];
            for (int h = 0; h < 128; ++h) {
                float u0 = a[h] * i0, u1 = a[128 + h] * i1;
                float u2 = a[256 + h] * i2, u3 = a[384 + h] * i3;
                float v = u0 + u1 + u2 + u3;
                lb += v * v - (u0 * u0 + u1 * u1 + u2 * u2 + u3 * u3);
            }
        }
        for (int off = 32; off; off >>= 1) lb += __shfl_down(lb, off);
        if (t == 0) o_loss[0] = lb / (float)(BB * DDk * (DDk - 1));
        return;
    }
    unsigned short* sa  = (unsigned short*)lds;              // 64x128 bf16
    unsigned short* sw  = (unsigned short*)(lds + 16384);    // 128x128 bf16
    float*          scp = (float*)lds;                       // 64x128 f32 (overlay)
    float*          sap = (float*)(lds + 49152);             // 32x128 f32
    float*          swv = (float*)(lds + 65536);             // 128 f32

    int tile = gid >> 2, d = gid & 3;
    int i0 = tile * 64;
    // stage sa: cand rows (zero-pad last tile)
#pragma unroll
    for (int q = 0; q < 4; ++q) {
        int x = t + q * 256;
        int r = x >> 4, ch = x & 15;
        short8 v = {0, 0, 0, 0, 0, 0, 0, 0};
        if (i0 + r < NI) v = *(const short8*)(Abf + (size_t)(NROWS_IN + i0 + r) * 128 + ch * 8);
        *(short8*)(sa + r * 128 + ((ch ^ (r & 15)) << 3)) = v;
    }
    // stage sw: Wcomb_d (Wcat rows 512+d*128 .. +128)
#pragma unroll
    for (int q = 0; q < 8; ++q) {
        int x = t + q * 256;
        int r = x >> 4, ch = x & 15;
        short8 v = *(const short8*)(Wcat + (size_t)(512 + d * 128 + r) * 128 + ch * 8);
        *(short8*)(sw + r * 128 + ((ch ^ (r & 15)) << 3)) = v;
    }
    // stage sap (ap rows for this d) + swv
    if (t < 128) swv[t] = wsc[t];
#pragma unroll
    for (int q = 0; q < 4; ++q) {
        int x = t + q * 256;                // 1024 float4s = 32x128 f32
        int b = x >> 5, ch = x & 31;
        float4 v = *(const float4*)(apw + (size_t)(b * 4 + d) * 128 + ch * 4);
        *(float4*)(&sap[b * 128 + ((ch ^ (b & 7)) << 2)]) = v;
    }
    __syncthreads();
    // GEMM: wave w: rows (w&1)*32, cols (w>>1)*64 (two 32x32 tiles)
    int w = t >> 6, lane = t & 63;
    int rbase = (w & 1) * 32, cbase = (w >> 1) * 64;
    int lr = lane & 31, g = lane >> 5;
    int arow = rbase + lr;
    int bcol0 = cbase + lr, bcol1 = cbase + 32 + lr;
    const unsigned short* pa  = sa + arow * 128;
    const unsigned short* pb0 = sw + bcol0 * 128;
    const unsigned short* pb1 = sw + bcol1 * 128;
    int axor = arow & 15, b0x = bcol0 & 15, b1x = bcol1 & 15;
    f32x16 acc0 = {}, acc1 = {};
#pragma unroll
    for (int ks = 0; ks < 8; ++ks) {
        int chA = ks * 2 + g;
        short8 a8 = *(const short8*)(pa  + ((chA ^ axor) << 3));
        short8 b8 = *(const short8*)(pb0 + ((chA ^ b0x) << 3));
        short8 c8 = *(const short8*)(pb1 + ((chA ^ b1x) << 3));
        acc0 = __builtin_amdgcn_mfma_f32_32x32x16_bf16(a8, b8, acc0, 0, 0, 0);
        acc1 = __builtin_amdgcn_mfma_f32_32x32x16_bf16(a8, c8, acc1, 0, 0, 0);
    }
    __syncthreads();                        // done reading sa/sw
    // scatter cp tile into scp (swizzled f32)
#pragma unroll
    for (int r = 0; r < 16; ++r) {
        int row = rbase + (r & 3) + 8 * (r >> 2) + 4 * g;
        int c0 = cbase + lr, c1 = cbase + 32 + lr;
        scp[row * 128 + ((((c0 >> 2) ^ (row & 7)) << 2) | (c0 & 3))] = acc0[r];
        scp[row * 128 + ((((c1 >> 2) ^ (row & 7)) << 2) | (c1 & 3))] = acc1[r];
    }
    __syncthreads();
    // score: thread (b = t>>3, gg = t&7) -> 8 i's
    int b = t >> 3, gg = t & 7;
    int bx = b & 7;
    float acc[8] = {0.f, 0.f, 0.f, 0.f, 0.f, 0.f, 0.f, 0.f};
    const float* arow2 = sap + b * 128;
    for (int ch = 0; ch < 32; ++ch) {
        float4 a4 = *(const float4*)(arow2 + ((ch ^ bx) << 2));
        float4 w4 = *(const float4*)(swv + ch * 4);
#pragma unroll
        for (int kk = 0; kk < 8; ++kk) {
            int il = kk * 8 + gg;
            float4 c4 = *(const float4*)(&scp[il * 128 + ((ch ^ (il & 7)) << 2)]);
            acc[kk] += w4.x * fmaxf(a4.x + c4.x, 0.f) + w4.y * fmaxf(a4.y + c4.y, 0.f)
                     + w4.z * fmaxf(a4.z + c4.z, 0.f) + w4.w * fmaxf(a4.w + c4.w, 0.f);
        }
    }
#pragma unroll
    for (int kk = 0; kk < 8; ++kk) {
        int i = i0 + kk * 8 + gg;
        if (i < NI) o_dsc[(size_t)b * (DDk * NI) + d * NI + i] = acc[kk];
    }
}

// ---------------------------------------------------------------------------
extern "C" void kernel_launch(void* const* d_in, const int* in_sizes, int n_in,
                              void* d_out, int out_size, void* d_ws, size_t ws_size,
                              hipStream_t stream) {
    const int*   inp  = (const int*)d_in[0];
    const int*   cand = (const int*)d_in[1];
    const float* et   = (const float*)d_in[2];
    const float* Wd   = (const float*)d_in[3];
    const float* Ws   = (const float*)d_in[4];
    const float* bsc  = (const float*)d_in[5];
    const float* wsc  = (const float*)d_in[6];

    float* out = (float*)d_out;
    float* o_ds   = out;                  // (B,D,S)    6400
    float* o_dsc  = out + 6400;           // (B,D,I)    640000
    float* o_emb  = out + 646400;         // (B,S,E)    204800
    float* o_cemb = out + 851200;         // (I,E)      640000
    float* o_loss = out + 1491200;        // scalar

    char* wsb = (char*)d_ws;
    unsigned short* Wcat = (unsigned short*)wsb;              // 1024x128 bf16
    unsigned short* Abf  = (unsigned short*)(wsb + 262144);   // 6600x128 bf16
    float* aggw = (float*)(wsb + 2097152);                    // 16384 f32
    float* apw  = aggw + 16384;                               // 16384 f32

    hipLaunchKernelGGL(k_prep, dim3(905), dim3(256), 0, stream,
                       inp, cand, et, Wd, Ws, Wcat, Abf, o_emb, o_cemb);
    hipLaunchKernelGGL(k_fused_mid, dim3(128), dim3(256), 0, stream,
                       Abf, Wcat, Ws, bsc, wsc, aggw, apw, o_ds);
    hipLaunchKernelGGL(k_cand, dim3(317), dim3(256), 0, stream,
                       Abf, Wcat, apw, aggw, wsc, o_dsc, o_loss);
}